// Round 7
// baseline (269.053 us; speedup 1.0000x reference)
//
#include <hip/hip_runtime.h>
#include <hip/hip_bf16.h>

#define BB 16
#define LOG2E 1.4426950408889634f

typedef __attribute__((ext_vector_type(8))) short bf16x8;
typedef __attribute__((ext_vector_type(4))) float f32x4;

__device__ __forceinline__ unsigned short f2bfbits(float f) {
    union { float f; unsigned u; } v; v.f = f;
    unsigned r = v.u + 0x7fffu + ((v.u >> 16) & 1u);   // RNE
    return (unsigned short)(r >> 16);
}
__device__ __forceinline__ float bfraw(unsigned short u) {
    union { unsigned u; float f; } v; v.u = ((unsigned)u) << 16; return v.f;
}
__device__ __forceinline__ unsigned packbf2(float lo, float hi) {
    return (unsigned)f2bfbits(lo) | ((unsigned)f2bfbits(hi) << 16);
}

// ---------------------------------------------------------------------------
// prep: fp32 params -> bf16 ws copies.
// ---------------------------------------------------------------------------
__global__ void prep_kernel(
    const float* __restrict__ wt, const float* __restrict__ bt,
    const float* __restrict__ wp, const float* __restrict__ bp,
    const float* __restrict__ wg, const float* __restrict__ bg,
    const float* __restrict__ wo,
    unsigned short* __restrict__ w_all, unsigned short* __restrict__ w_o_bf,
    float* __restrict__ b_all)
{
    int i = blockIdx.x * 256 + threadIdx.x;
    if (i < 8192)        w_all[i] = f2bfbits(wt[i]);
    else if (i < 16384)  w_all[i] = f2bfbits(wp[i - 8192]);
    else if (i < 49152)  w_all[i] = f2bfbits(wg[i - 16384]);
    else if (i < 81920)  w_o_bf[i - 49152] = f2bfbits(wo[i - 49152]);
    else if (i < 82112) {
        int r = i - 81920;
        b_all[r] = (r < 32) ? bt[r] : (r < 64) ? bp[r - 32] : bg[r - 64];
    }
}

// ---------------------------------------------------------------------------
// xT v2 (coalesced): x fp32 [B][256][4096] -> x_t bf16 [B][4096][256].
// ---------------------------------------------------------------------------
__global__ __launch_bounds__(256) void xt_kernel(
    const float* __restrict__ x, unsigned short* __restrict__ x_t)
{
    __shared__ unsigned short lt[64 * 258];   // [c][p] stride 258

    const int t = threadIdx.x;
    const int bid = blockIdx.x;
    const int b  = bid >> 6;
    const int pt = (bid >> 2) & 15;
    const int ct = bid & 3;
    const int p0 = pt << 8;
    const int c0 = ct << 6;

    {
        int c = t >> 2, qf = t & 3;
        const float* src = x + ((size_t)(b * 256 + c0 + c)) * 4096 + p0 + qf * 4;
        unsigned short* dst = lt + c * 258 + qf * 4;
        #pragma unroll
        for (int j = 0; j < 16; ++j) {
            float4 v = *(const float4*)(src + j * 16);
            unsigned* d = (unsigned*)(dst + j * 16);
            d[0] = packbf2(v.x, v.y);
            d[1] = packbf2(v.z, v.w);
        }
    }
    __syncthreads();
    {
        int p8 = t >> 3, c8 = t & 7;
        #pragma unroll
        for (int i = 0; i < 8; ++i) {
            int p = p8 + 32 * i;
            union { int4 v; unsigned short u[8]; } o;
            #pragma unroll
            for (int e = 0; e < 8; ++e) o.u[e] = lt[(c8 * 8 + e) * 258 + p];
            *(int4*)(x_t + ((size_t)(b * 4096 + p0 + p)) * 256 + c0 + c8 * 8) = o.v;
        }
    }
}

// ---------------------------------------------------------------------------
// proj: [192 co] x [256 cin] x [128 pos/block] MFMA GEMM + bias + pool.
// theta rows pre-scaled by LOG2E (softmax in exp2 domain).
// ---------------------------------------------------------------------------
__global__ __launch_bounds__(256, 2) void proj_kernel(
    const unsigned short* __restrict__ x_t,
    const unsigned short* __restrict__ w_all,
    const float* __restrict__ b_all,
    unsigned short* __restrict__ theta_t,   // [B][4096][32]  (x LOG2E)
    unsigned short* __restrict__ phi_t,     // [B][1024][32]
    unsigned short* __restrict__ g)         // [B][128][1024]
{
    __shared__ unsigned short ot[192 * 136];

    const int t = threadIdx.x;
    const int w = t >> 6;
    const int l = t & 63;
    const int lr = l & 15, lg = l >> 4;
    const int b  = blockIdx.x >> 5;
    const int pt = blockIdx.x & 31;
    const int pbase = pt << 7;
    const int mb = pt << 5;

    f32x4 acc[3][8];
    #pragma unroll
    for (int i = 0; i < 3; ++i)
        #pragma unroll
        for (int nt = 0; nt < 8; ++nt) acc[i][nt] = (f32x4){0.f,0.f,0.f,0.f};

    #pragma unroll 2
    for (int ks = 0; ks < 8; ++ks) {
        bf16x8 af[3];
        #pragma unroll
        for (int i = 0; i < 3; ++i)
            af[i] = *(const bf16x8*)(w_all + (size_t)(16*(3*w+i) + lr)*256 + 32*ks + 8*lg);
        #pragma unroll
        for (int nt = 0; nt < 8; ++nt) {
            bf16x8 bx = *(const bf16x8*)(x_t + ((size_t)(b*4096 + pbase + 16*nt + lr))*256 + 32*ks + 8*lg);
            #pragma unroll
            for (int i = 0; i < 3; ++i)
                acc[i][nt] = __builtin_amdgcn_mfma_f32_16x16x32_bf16(af[i], bx, acc[i][nt], 0, 0, 0);
        }
    }

    float bias[3][4];
    #pragma unroll
    for (int i = 0; i < 3; ++i)
        #pragma unroll
        for (int r = 0; r < 4; ++r) bias[i][r] = b_all[16*(3*w+i) + 4*lg + r];
    #pragma unroll
    for (int i = 0; i < 3; ++i) {
        const float scale = (3*w + i < 2) ? LOG2E : 1.0f;   // theta tiles only
        #pragma unroll
        for (int nt = 0; nt < 8; ++nt)
            #pragma unroll
            for (int r = 0; r < 4; ++r)
                ot[(16*(3*w+i) + 4*lg + r)*136 + 16*nt + lr] =
                    f2bfbits((acc[i][nt][r] + bias[i][r]) * scale);
    }
    __syncthreads();

    if (t < 128) {
        int p = t;
        union { unsigned short u[32]; int4 v[4]; } th;
        #pragma unroll
        for (int c = 0; c < 32; ++c) th.u[c] = ot[c*136 + p];
        int4* dst = (int4*)(theta_t + ((size_t)(b*4096 + pbase + p)) * 32);
        #pragma unroll
        for (int q = 0; q < 4; ++q) dst[q] = th.v[q];
    }
    {
        int ww = t >> 3, c0 = (t & 7) * 4;
        union { unsigned short u[4]; int2 v; } ph;
        #pragma unroll
        for (int e = 0; e < 4; ++e) {
            int row = 32 + c0 + e;
            unsigned p01 = *(const unsigned*)&ot[row*136 + 2*ww];
            unsigned p23 = *(const unsigned*)&ot[row*136 + 64 + 2*ww];
            float m0 = fmaxf(bfraw((unsigned short)p01), bfraw((unsigned short)(p01 >> 16)));
            float m1 = fmaxf(bfraw((unsigned short)p23), bfraw((unsigned short)(p23 >> 16)));
            ph.u[e] = f2bfbits(fmaxf(m0, m1));
        }
        *(int2*)(phi_t + ((size_t)(b*1024 + mb + ww)) * 32 + c0) = ph.v;
    }
    {
        int c2 = t >> 1, w0 = (t & 1) * 16;
        int row = 64 + c2;
        union { unsigned short u[16]; int4 v[2]; } gv;
        #pragma unroll
        for (int e = 0; e < 16; ++e) {
            int ww = w0 + e;
            unsigned p01 = *(const unsigned*)&ot[row*136 + 2*ww];
            unsigned p23 = *(const unsigned*)&ot[row*136 + 64 + 2*ww];
            float m0 = fmaxf(bfraw((unsigned short)p01), bfraw((unsigned short)(p01 >> 16)));
            float m1 = fmaxf(bfraw((unsigned short)p23), bfraw((unsigned short)(p23 >> 16)));
            gv.u[e] = f2bfbits(fmaxf(m0, m1));
        }
        int4* dst = (int4*)(g + ((size_t)(b*128 + c2)) * 1024 + mb + w0);
        dst[0] = gv.v[0]; dst[1] = gv.v[1];
    }
}

// ---------------------------------------------------------------------------
// attn v4: key-split x2. Each wave: 32 q, 512 keys (8 chunks of 64).
// Swapped QK^T, exp2-domain online softmax, reg-prefetch of g and phi.
// Writes UNNORMALIZED partial o (bf16) + per-(split,n) {m,l}.
// ---------------------------------------------------------------------------
__global__ __launch_bounds__(256, 2) void attn_kernel(
    const unsigned short* __restrict__ theta_t,
    const unsigned short* __restrict__ phi_t,
    const unsigned short* __restrict__ g,
    unsigned short* __restrict__ o_part,   // [2][B*4096][128]
    float2* __restrict__ msl)              // [2][B*4096]
{
    __shared__ unsigned short smem[4 * 4352];

    const int t = threadIdx.x;
    const int wv = t >> 6;
    const int l  = t & 63;
    const int lr = l & 15, lg = l >> 4;
    const int bid = blockIdx.x;
    const int b   = bid >> 6;
    const int s   = (bid >> 5) & 1;
    const int nq0 = (bid & 31) * 128 + wv * 32;
    const int kbase = s * 512;

    unsigned short* pw = smem + wv * 4352;
    unsigned short* ow = smem + wv * 4352;

    const f32x4 zero = {0.f, 0.f, 0.f, 0.f};

    bf16x8 aq[2];
    #pragma unroll
    for (int qt = 0; qt < 2; ++qt)
        aq[qt] = *(const bf16x8*)(theta_t + ((size_t)(b*4096 + nq0 + 16*qt + lr))*32 + 8*lg);

    f32x4 po[2][8];
    #pragma unroll
    for (int qt = 0; qt < 2; ++qt)
        #pragma unroll
        for (int ct = 0; ct < 8; ++ct) po[qt][ct] = zero;
    float m_run[2] = {-1e30f, -1e30f}, l_run[2] = {0.f, 0.f};

    const unsigned short* phb = phi_t + (size_t)b * 1024 * 32;
    const unsigned short* gb  = g + (size_t)b * 128 * 1024;

    bf16x8 pf[4];
    #pragma unroll
    for (int mt = 0; mt < 4; ++mt)
        pf[mt] = *(const bf16x8*)(phb + (size_t)(kbase + 16*mt + lr)*32 + 8*lg);

    #pragma unroll 1
    for (int kt = 0; kt < 8; ++kt) {
        const int mb = kbase + kt * 64;
        bf16x8 gv[16];
        #pragma unroll
        for (int ks = 0; ks < 2; ++ks)
            #pragma unroll
            for (int ct = 0; ct < 8; ++ct)
                gv[ks*8 + ct] = *(const bf16x8*)(gb + (size_t)(16*ct + lr)*1024 + mb + 32*ks + 8*lg);

        f32x4 sv[2][4];
        #pragma unroll
        for (int mt = 0; mt < 4; ++mt) {
            sv[0][mt] = __builtin_amdgcn_mfma_f32_16x16x32_bf16(pf[mt], aq[0], zero, 0, 0, 0);
            sv[1][mt] = __builtin_amdgcn_mfma_f32_16x16x32_bf16(pf[mt], aq[1], zero, 0, 0, 0);
        }
        {
            const int mbn = (kt < 7) ? mb + 64 : mb;
            #pragma unroll
            for (int mt = 0; mt < 4; ++mt)
                pf[mt] = *(const bf16x8*)(phb + (size_t)(mbn + 16*mt + lr)*32 + 8*lg);
        }

        float scv[2];
        #pragma unroll
        for (int qt = 0; qt < 2; ++qt) {
            float mx = -1e30f;
            #pragma unroll
            for (int mt = 0; mt < 4; ++mt)
                #pragma unroll
                for (int r = 0; r < 4; ++r) mx = fmaxf(mx, sv[qt][mt][r]);
            mx = fmaxf(mx, __shfl_xor(mx, 16));
            mx = fmaxf(mx, __shfl_xor(mx, 32));
            float nm = fmaxf(m_run[qt], mx);
            float sc = exp2f(m_run[qt] - nm);
            float ls = 0.f;
            #pragma unroll
            for (int mt = 0; mt < 4; ++mt)
                #pragma unroll
                for (int r = 0; r < 4; ++r) {
                    float p = exp2f(sv[qt][mt][r] - nm);
                    sv[qt][mt][r] = p; ls += p;
                }
            ls += __shfl_xor(ls, 16);
            ls += __shfl_xor(ls, 32);
            l_run[qt] = l_run[qt] * sc + ls;
            m_run[qt] = nm;
            scv[qt] = sc;
        }
        #pragma unroll
        for (int qt = 0; qt < 2; ++qt) {
            float scB[4];
            #pragma unroll
            for (int r = 0; r < 4; ++r) scB[r] = __shfl(scv[qt], 4*lg + r);
            #pragma unroll
            for (int ct = 0; ct < 8; ++ct)
                #pragma unroll
                for (int r = 0; r < 4; ++r) po[qt][ct][r] *= scB[r];
        }
        #pragma unroll
        for (int qt = 0; qt < 2; ++qt)
            #pragma unroll
            for (int mt = 0; mt < 4; ++mt)
                #pragma unroll
                for (int i = 0; i < 2; ++i)
                    *(unsigned*)(pw + (16*qt + lr)*72 + 16*mt + 4*lg + 2*i) =
                        packbf2(sv[qt][mt][2*i], sv[qt][mt][2*i + 1]);
        #pragma unroll
        for (int ks = 0; ks < 2; ++ks) {
            bf16x8 pa0 = *(const bf16x8*)(pw + (size_t)lr*72 + 32*ks + 8*lg);
            bf16x8 pa1 = *(const bf16x8*)(pw + (size_t)(16 + lr)*72 + 32*ks + 8*lg);
            #pragma unroll
            for (int ct = 0; ct < 8; ++ct) {
                po[0][ct] = __builtin_amdgcn_mfma_f32_16x16x32_bf16(pa0, gv[ks*8+ct], po[0][ct], 0, 0, 0);
                po[1][ct] = __builtin_amdgcn_mfma_f32_16x16x32_bf16(pa1, gv[ks*8+ct], po[1][ct], 0, 0, 0);
            }
        }
    }

    const size_t nglob = (size_t)s * 65536 + (size_t)b * 4096 + nq0;
    if (lg == 0) {
        #pragma unroll
        for (int qt = 0; qt < 2; ++qt)
            msl[nglob + 16*qt + lr] = float2{m_run[qt], l_run[qt]};
    }
    #pragma unroll
    for (int qt = 0; qt < 2; ++qt)
        #pragma unroll
        for (int ct = 0; ct < 8; ++ct)
            #pragma unroll
            for (int r = 0; r < 4; ++r)
                ow[(16*qt + 4*lg + r)*136 + 16*ct + lr] = f2bfbits(po[qt][ct][r]);
    #pragma unroll
    for (int i = 0; i < 8; ++i) {
        int q = 4*i + lg;
        int4 v = *(const int4*)(ow + q*136 + 8*lr);
        *(int4*)(o_part + (nglob + q)*128 + 8*lr) = v;
    }
}

// ---------------------------------------------------------------------------
// combine: merge key-split partials -> normalized o_pre bf16.
// FIXED: 16 threads x 8 ch = 128 channels per n (was 8x8=64 -> half poisoned).
// ---------------------------------------------------------------------------
__global__ __launch_bounds__(256) void combine_kernel(
    const unsigned short* __restrict__ o_part,
    const float2* __restrict__ msl,
    unsigned short* __restrict__ o_pre)
{
    const int t = threadIdx.x;
    const int n = blockIdx.x * 16 + (t >> 4);
    const int c8 = (t & 15) * 8;

    float2 s0 = msl[n];
    float2 s1 = msl[65536 + n];
    float M  = fmaxf(s0.x, s1.x);
    float w0 = exp2f(s0.x - M), w1 = exp2f(s1.x - M);
    float inv = 1.f / (w0 * s0.y + w1 * s1.y);
    float a0 = w0 * inv, a1 = w1 * inv;

    union { int4 v; unsigned short u[8]; } p0, p1, o;
    p0.v = *(const int4*)(o_part + (size_t)n * 128 + c8);
    p1.v = *(const int4*)(o_part + ((size_t)65536 + n) * 128 + c8);
    #pragma unroll
    for (int e = 0; e < 8; ++e)
        o.u[e] = f2bfbits(a0 * bfraw(p0.u[e]) + a1 * bfraw(p1.u[e]));
    *(int4*)(o_pre + (size_t)n * 128 + c8) = o.v;
}

// ---------------------------------------------------------------------------
// out: GEMM [co] x [128 c2] x [n] + gamma*o + x. co-split x2.
// ---------------------------------------------------------------------------
__global__ __launch_bounds__(256, 4) void out_kernel(
    const unsigned short* __restrict__ o_pre_t,
    const unsigned short* __restrict__ w_o_bf,
    const float* __restrict__ b_o,
    const float* __restrict__ x,
    const float* __restrict__ gamma,
    float* __restrict__ out)
{
    const int t = threadIdx.x;
    const int w = t >> 6, l = t & 63;
    const int lr = l & 15, lg = l >> 4;
    const int bid = blockIdx.x;
    const int b    = bid >> 7;
    const int half = (bid >> 6) & 1;
    const int nbv  = (bid & 63) << 6;

    f32x4 acc[2][4];
    #pragma unroll
    for (int i = 0; i < 2; ++i)
        #pragma unroll
        for (int nt = 0; nt < 4; ++nt) acc[i][nt] = (f32x4){0.f,0.f,0.f,0.f};

    #pragma unroll 2
    for (int ks = 0; ks < 4; ++ks) {
        bf16x8 aw[2], bo[4];
        #pragma unroll
        for (int i = 0; i < 2; ++i) {
            int cot = half * 8 + 2*w + i;
            aw[i] = *(const bf16x8*)(w_o_bf + (size_t)(16*cot + lr)*128 + 32*ks + 8*lg);
        }
        #pragma unroll
        for (int nt = 0; nt < 4; ++nt)
            bo[nt] = *(const bf16x8*)(o_pre_t + ((size_t)(b*4096 + nbv + 16*nt + lr))*128 + 32*ks + 8*lg);
        #pragma unroll
        for (int i = 0; i < 2; ++i)
            #pragma unroll
            for (int nt = 0; nt < 4; ++nt)
                acc[i][nt] = __builtin_amdgcn_mfma_f32_16x16x32_bf16(aw[i], bo[nt], acc[i][nt], 0, 0, 0);
    }

    const float gam = gamma[0];
    #pragma unroll
    for (int i = 0; i < 2; ++i) {
        int cot = half * 8 + 2*w + i;
        #pragma unroll
        for (int nt = 0; nt < 4; ++nt)
            #pragma unroll
            for (int r = 0; r < 4; ++r) {
                int co = 16*cot + 4*lg + r;
                int n  = nbv + 16*nt + lr;
                size_t off = ((size_t)(b*256 + co)) * 4096 + n;
                out[off] = gam * (acc[i][nt][r] + b_o[co]) + x[off];
            }
    }
}

// ---------------------------------------------------------------------------
extern "C" void kernel_launch(void* const* d_in, const int* in_sizes, int n_in,
                              void* d_out, int out_size, void* d_ws, size_t ws_size,
                              hipStream_t stream)
{
    const float* x       = (const float*)d_in[0];
    const float* w_theta = (const float*)d_in[1];
    const float* b_theta = (const float*)d_in[2];
    const float* w_phi   = (const float*)d_in[3];
    const float* b_phi   = (const float*)d_in[4];
    const float* w_g     = (const float*)d_in[5];
    const float* b_g     = (const float*)d_in[6];
    const float* w_o     = (const float*)d_in[7];
    const float* b_o     = (const float*)d_in[8];
    const float* gamma   = (const float*)d_in[9];
    float* outp = (float*)d_out;

    char* ws = (char*)d_ws;
    unsigned short* w_all   = (unsigned short*)ws;                  // 96 KB
    unsigned short* w_o_bf  = (unsigned short*)(ws + 98304);        // 64 KB
    float*          b_all   = (float*)(ws + 163840);                // 768 B
    unsigned short* x_t     = (unsigned short*)(ws + (1u << 20));   // 32 MB [B][4096][256]
    unsigned short* o_part  = (unsigned short*)(ws + (1u << 20));   // 32 MB (aliases x_t; disjoint lifetime)
    unsigned short* theta_t = (unsigned short*)(ws + (33u << 20));  // 4 MB
    unsigned short* phi_t   = (unsigned short*)(ws + (37u << 20));  // 1 MB
    unsigned short* g       = (unsigned short*)(ws + (38u << 20));  // 4 MB
    unsigned short* o_pre   = (unsigned short*)(ws + (33u << 20));  // 16 MB (aliases theta/phi/g; dead by then)
    float2*         msl     = (float2*)(ws + (49u << 20));          // 1 MB

    prep_kernel<<<321, 256, 0, stream>>>(w_theta, b_theta, w_phi, b_phi,
                                         w_g, b_g, w_o, w_all, w_o_bf, b_all);
    xt_kernel<<<BB * 64, 256, 0, stream>>>(x, x_t);
    proj_kernel<<<BB * 32, 256, 0, stream>>>(x_t, w_all, b_all, theta_t, phi_t, g);
    attn_kernel<<<BB * 64, 256, 0, stream>>>(theta_t, phi_t, g, o_part, msl);
    combine_kernel<<<4096, 256, 0, stream>>>(o_part, msl, o_pre);
    out_kernel<<<BB * 128, 256, 0, stream>>>(o_pre, w_o_bf, b_o, x, gamma, outp);
}